// Round 4
// baseline (121.492 us; speedup 1.0000x reference)
//
#include <hip/hip_runtime.h>
#include <math.h>

// Problem: x is (64, 1048576) f32 = 64M elements. Reference returns True
// iff argmax-with-lowest-index-ties != argmax-with-highest-index-ties, i.e.
// iff the global maximum value occurs at more than one index.
// Output dtype is bool -> harness reads d_out as int32. Store int 0/1.
//
// Single fused kernel (round-2: separate finalize launch cost ~4-5us):
// per-block tie-aware argmax -> two packed u64 atomicMax slots
//   kmax key = (mapped_value << 32) | idx        (max -> highest idx at max v)
//   kmin key = (mapped_value << 32) | ~idx       (max -> lowest  idx at max v)
// mapped_value = monotone u32 mapping of f32 (sign-flip trick), so any real
// float maps > 0 and the zero-initialized slots are always dominated.
// Last block (ticket) reads slots after device fence, writes verdict.
// d_ws slots are zeroed each call via a 24B hipMemsetAsync (graph-capturable).

#define NB 2048   // blocks; 8 blocks/CU on 256 CUs
#define NT 256    // threads per block (4 waves)

struct Ctl { unsigned long long kmin; unsigned long long kmax; unsigned int ticket; };

__device__ __forceinline__ void upd(float x, int idx, float& v, int& imin, int& imax) {
    if (x > v)      { v = x; imin = idx; imax = idx; }
    else if (x == v){ if (idx < imin) imin = idx; if (idx > imax) imax = idx; }
}

__device__ __forceinline__ void merge(float bv, int bmn, int bmx,
                                      float& v, int& imin, int& imax) {
    if (bv > v)       { v = bv; imin = bmn; imax = bmx; }
    else if (bv == v) { if (bmn < imin) imin = bmn; if (bmx > imax) imax = bmx; }
}

// Monotone map: f32 -> u32 preserving order (NaN-free input).
__device__ __forceinline__ unsigned int fmap(float f) {
    unsigned int u = __float_as_uint(f);
    return (u & 0x80000000u) ? ~u : (u | 0x80000000u);
}

__global__ __launch_bounds__(NT) void argmax_fused(const float4* __restrict__ x,
                                                   Ctl* __restrict__ ctl,
                                                   int n4, int n,
                                                   int* __restrict__ out) {
    const int tid = blockIdx.x * NT + threadIdx.x;
    const int stride = NB * NT;
    float v = -INFINITY; int imin = 0x7fffffff, imax = -1;
    for (int i = tid; i < n4; i += stride) {
        float4 f = x[i];
        int b = i << 2;
        upd(f.x, b,     v, imin, imax);
        upd(f.y, b + 1, v, imin, imax);
        upd(f.z, b + 2, v, imin, imax);
        upd(f.w, b + 3, v, imin, imax);
    }
    // Tail (n % 4 != 0) — none for this shape, but be safe.
    if (blockIdx.x == 0) {
        const float* xs = (const float*)x;
        for (int i = n4 * 4 + threadIdx.x; i < n; i += NT) upd(xs[i], i, v, imin, imax);
    }

    __shared__ float sv[NT];
    __shared__ int   smn[NT], smx[NT];
    const int t = threadIdx.x;
    sv[t] = v; smn[t] = imin; smx[t] = imax;
    __syncthreads();
    for (int s = NT / 2; s > 0; s >>= 1) {
        if (t < s) {
            float av = sv[t]; int amn = smn[t], amx = smx[t];
            merge(sv[t + s], smn[t + s], smx[t + s], av, amn, amx);
            sv[t] = av; smn[t] = amn; smx[t] = amx;
        }
        __syncthreads();
    }

    if (t == 0) {
        unsigned long long mv = (unsigned long long)fmap(sv[0]) << 32;
        atomicMax(&ctl->kmin, mv | (unsigned int)(~smn[0]));
        atomicMax(&ctl->kmax, mv | (unsigned int)( smx[0]));
        __threadfence();
        unsigned int old = atomicAdd(&ctl->ticket, 1u);
        if (old == NB - 1) {
            __threadfence();
            unsigned long long kmin = atomicMax(&ctl->kmin, 0ULL);  // atomic read
            unsigned long long kmax = atomicMax(&ctl->kmax, 0ULL);
            int gimin = (int)(~(unsigned int)kmin);
            int gimax = (int)( (unsigned int)kmax);
            out[0] = (gimin != gimax) ? 1 : 0;
        }
    }
}

extern "C" void kernel_launch(void* const* d_in, const int* in_sizes, int n_in,
                              void* d_out, int out_size, void* d_ws, size_t ws_size,
                              hipStream_t stream) {
    const float* x = (const float*)d_in[0];
    const int n  = in_sizes[0];      // 67108864
    const int n4 = n >> 2;
    Ctl* ctl = (Ctl*)d_ws;

    (void)hipMemsetAsync(d_ws, 0, sizeof(Ctl), stream);   // zero slots + ticket each call
    argmax_fused<<<NB, NT, 0, stream>>>((const float4*)x, ctl, n4, n, (int*)d_out);
}

// Round 5
// 55.896 us; speedup vs baseline: 2.1735x; 2.1735x over previous
//
#include <hip/hip_runtime.h>
#include <math.h>

// Problem: x is (64, 1048576) f32 = 64M elements. Reference returns True
// iff argmax-with-lowest-index-ties != argmax-with-highest-index-ties, i.e.
// iff the global maximum value occurs at more than one index.
// Output dtype is bool -> harness reads d_out as int32. Store int 0/1.
//
// Round-4 lesson: fused single-kernel with same-line device atomics from all
// 2048 co-resident blocks serializes ~6144 RMWs x ~20ns = +125us tail (zero-
// fetch dispatches still took ~170us). Two-kernel structure with distinct-
// address partial stores + tiny finalize launch (~4us) is far cheaper.
// This round: 4x unrolled main loop (4 independent float4 loads in flight).

#define NB 2048   // blocks; 8 blocks/CU on 256 CUs (all co-resident)
#define NT 256    // threads per block (4 waves)

struct Trip { float v; int imin; int imax; };

__device__ __forceinline__ void upd(float x, int idx, float& v, int& imin, int& imax) {
    if (x > v)      { v = x; imin = idx; imax = idx; }
    else if (x == v){ if (idx < imin) imin = idx; if (idx > imax) imax = idx; }
}

__device__ __forceinline__ void upd4(const float4& f, int b, float& v, int& imin, int& imax) {
    upd(f.x, b,     v, imin, imax);
    upd(f.y, b + 1, v, imin, imax);
    upd(f.z, b + 2, v, imin, imax);
    upd(f.w, b + 3, v, imin, imax);
}

__device__ __forceinline__ void merge(float bv, int bmn, int bmx,
                                      float& v, int& imin, int& imax) {
    if (bv > v)       { v = bv; imin = bmn; imax = bmx; }
    else if (bv == v) { if (bmn < imin) imin = bmn; if (bmx > imax) imax = bmx; }
}

__global__ __launch_bounds__(NT) void argmax_part(const float4* __restrict__ x,
                                                  Trip* __restrict__ part, int n4) {
    const int tid = blockIdx.x * NT + threadIdx.x;
    const int stride = NB * NT;
    float v = -INFINITY; int imin = 0x7fffffff, imax = -1;

    if ((n4 & (4 * stride - 1)) == 0) {
        // Fast path: n4 divisible by 4*stride (true for n=64M: 16M / 2M = 8 iters).
        for (int i = tid; i < n4; i += 4 * stride) {
            float4 a = x[i];
            float4 b = x[i + stride];
            float4 c = x[i + 2 * stride];
            float4 d = x[i + 3 * stride];
            upd4(a, i << 2,                  v, imin, imax);
            upd4(b, (i + stride) << 2,       v, imin, imax);
            upd4(c, (i + 2 * stride) << 2,   v, imin, imax);
            upd4(d, (i + 3 * stride) << 2,   v, imin, imax);
        }
    } else {
        for (int i = tid; i < n4; i += stride) {
            float4 f = x[i];
            upd4(f, i << 2, v, imin, imax);
        }
    }

    __shared__ float sv[NT];
    __shared__ int   smn[NT], smx[NT];
    const int t = threadIdx.x;
    sv[t] = v; smn[t] = imin; smx[t] = imax;
    __syncthreads();
    for (int s = NT / 2; s > 0; s >>= 1) {
        if (t < s) {
            float av = sv[t]; int amn = smn[t], amx = smx[t];
            merge(sv[t + s], smn[t + s], smx[t + s], av, amn, amx);
            sv[t] = av; smn[t] = amn; smx[t] = amx;
        }
        __syncthreads();
    }
    if (t == 0) { part[blockIdx.x].v = sv[0]; part[blockIdx.x].imin = smn[0]; part[blockIdx.x].imax = smx[0]; }
}

__global__ __launch_bounds__(NT) void argmax_final(const Trip* __restrict__ part,
                                                   const float* __restrict__ x,
                                                   int n4, int n,
                                                   int* __restrict__ out) {
    const int t = threadIdx.x;
    float v = -INFINITY; int imin = 0x7fffffff, imax = -1;
    for (int i = t; i < NB; i += NT) {
        Trip p = part[i];
        merge(p.v, p.imin, p.imax, v, imin, imax);
    }
    // Tail elements (n not divisible by 4) — none for this shape, but be safe.
    for (int i = n4 * 4 + t; i < n; i += NT) upd(x[i], i, v, imin, imax);

    __shared__ float sv[NT];
    __shared__ int   smn[NT], smx[NT];
    sv[t] = v; smn[t] = imin; smx[t] = imax;
    __syncthreads();
    for (int s = NT / 2; s > 0; s >>= 1) {
        if (t < s) {
            float av = sv[t]; int amn = smn[t], amx = smx[t];
            merge(sv[t + s], smn[t + s], smx[t + s], av, amn, amx);
            sv[t] = av; smn[t] = amn; smx[t] = amx;
        }
        __syncthreads();
    }
    if (t == 0) out[0] = (smn[0] != smx[0]) ? 1 : 0;
}

extern "C" void kernel_launch(void* const* d_in, const int* in_sizes, int n_in,
                              void* d_out, int out_size, void* d_ws, size_t ws_size,
                              hipStream_t stream) {
    const float* x = (const float*)d_in[0];
    const int n  = in_sizes[0];      // 67108864
    const int n4 = n >> 2;
    Trip* part = (Trip*)d_ws;        // 2048 * 12 B = 24 KiB scratch

    argmax_part <<<NB, NT, 0, stream>>>((const float4*)x, part, n4);
    argmax_final<<<1,  NT, 0, stream>>>(part, x, n4, n, (int*)d_out);
}

// Round 6
// 49.166 us; speedup vs baseline: 2.4711x; 1.1369x over previous
//
#include <hip/hip_runtime.h>
#include <math.h>

// Problem: x is (64, 1048576) f32 = 64M elements. Reference returns True
// iff argmax-with-lowest-index-ties != argmax-with-highest-index-ties, i.e.
// iff the global maximum value occurs at more than one index.
// Output dtype is bool -> harness reads d_out as int32. Store int 0/1.
//
// Journal: R2 two-kernel grid-stride float4 = 49.35us (best). R4 fused with
// same-line device atomics = 121us (2048-block atomic tail ~20ns/RMW). R5
// 4x strided unroll = 55.9us (channel aliasing at 8MB pow2 stride; TLP was
// already saturating). This round: R2 pattern + wave-shuffle block reduce
// (shorter tail than 8-round LDS tree) + 16B-padded partials (dwordx4).

#define NB 2048   // blocks; 8 blocks/CU on 256 CUs = 32 waves/CU (max occupancy)
#define NT 256    // threads per block (4 waves)

struct Trip16 { float v; int imin; int imax; int pad; };  // 16B for dwordx4

__device__ __forceinline__ void upd(float x, int idx, float& v, int& imin, int& imax) {
    if (x > v)      { v = x; imin = idx; imax = idx; }
    else if (x == v){ if (idx < imin) imin = idx; if (idx > imax) imax = idx; }
}

__device__ __forceinline__ void merge(float bv, int bmn, int bmx,
                                      float& v, int& imin, int& imax) {
    if (bv > v)       { v = bv; imin = bmn; imax = bmx; }
    else if (bv == v) { if (bmn < imin) imin = bmn; if (bmx > imax) imax = bmx; }
}

// 64-lane butterfly reduce of (v, imin, imax) — register-only.
__device__ __forceinline__ void wave_reduce(float& v, int& imin, int& imax) {
    #pragma unroll
    for (int m = 32; m > 0; m >>= 1) {
        float ov = __shfl_xor(v, m, 64);
        int omn   = __shfl_xor(imin, m, 64);
        int omx   = __shfl_xor(imax, m, 64);
        merge(ov, omn, omx, v, imin, imax);
    }
}

__global__ __launch_bounds__(NT) void argmax_part(const float4* __restrict__ x,
                                                  Trip16* __restrict__ part, int n4) {
    const int tid = blockIdx.x * NT + threadIdx.x;
    const int stride = NB * NT;
    float v = -INFINITY; int imin = 0x7fffffff, imax = -1;
    for (int i = tid; i < n4; i += stride) {
        float4 f = x[i];
        int b = i << 2;
        upd(f.x, b,     v, imin, imax);
        upd(f.y, b + 1, v, imin, imax);
        upd(f.z, b + 2, v, imin, imax);
        upd(f.w, b + 3, v, imin, imax);
    }

    wave_reduce(v, imin, imax);

    __shared__ float sv[NT / 64];
    __shared__ int   smn[NT / 64], smx[NT / 64];
    const int lane = threadIdx.x & 63;
    const int wid  = threadIdx.x >> 6;
    if (lane == 0) { sv[wid] = v; smn[wid] = imin; smx[wid] = imax; }
    __syncthreads();
    if (threadIdx.x == 0) {
        #pragma unroll
        for (int w = 1; w < NT / 64; ++w) merge(sv[w], smn[w], smx[w], v, imin, imax);
        float4 p;
        p.x = v; p.y = __int_as_float(imin); p.z = __int_as_float(imax); p.w = 0.0f;
        *reinterpret_cast<float4*>(&part[blockIdx.x]) = p;
    }
}

__global__ __launch_bounds__(NT) void argmax_final(const float4* __restrict__ part,
                                                   const float* __restrict__ x,
                                                   int n4, int n,
                                                   int* __restrict__ out) {
    const int t = threadIdx.x;
    float v = -INFINITY; int imin = 0x7fffffff, imax = -1;
    #pragma unroll
    for (int k = 0; k < NB / NT; ++k) {
        float4 p = part[t + k * NT];
        merge(p.x, __float_as_int(p.y), __float_as_int(p.z), v, imin, imax);
    }
    // Tail elements (n not divisible by 4) — none for this shape, but be safe.
    for (int i = n4 * 4 + t; i < n; i += NT) upd(x[i], i, v, imin, imax);

    wave_reduce(v, imin, imax);

    __shared__ float sv[NT / 64];
    __shared__ int   smn[NT / 64], smx[NT / 64];
    const int lane = t & 63;
    const int wid  = t >> 6;
    if (lane == 0) { sv[wid] = v; smn[wid] = imin; smx[wid] = imax; }
    __syncthreads();
    if (t == 0) {
        #pragma unroll
        for (int w = 1; w < NT / 64; ++w) merge(sv[w], smn[w], smx[w], v, imin, imax);
        out[0] = (imin != imax) ? 1 : 0;
    }
}

extern "C" void kernel_launch(void* const* d_in, const int* in_sizes, int n_in,
                              void* d_out, int out_size, void* d_ws, size_t ws_size,
                              hipStream_t stream) {
    const float* x = (const float*)d_in[0];
    const int n  = in_sizes[0];      // 67108864
    const int n4 = n >> 2;
    Trip16* part = (Trip16*)d_ws;    // 2048 * 16 B = 32 KiB scratch

    argmax_part <<<NB, NT, 0, stream>>>((const float4*)x, part, n4);
    argmax_final<<<1,  NT, 0, stream>>>((const float4*)part, x, n4, n, (int*)d_out);
}